// Round 1
// baseline (1380.875 us; speedup 1.0000x reference)
//
#include <hip/hip_runtime.h>
#include <math.h>

#define Sn 100
#define Bn 128
#define NWc 430500
#define NBc 580
#define EWc 431080   // NW + NB

__device__ __forceinline__ float sp_f(float r){
    // stable softplus: log1p(exp(r))
    return fmaxf(r, 0.f) + log1pf(__expf(-fabsf(r)));
}

// ---------------- K0: materialize small params ----------------
// w1: S*500 (oc,ky,kx), w2: S*25000 (oc-major), w4: S*5000, ball: S*580
__global__ void k0_gen(const float* __restrict__ e, const float* __restrict__ mu_w,
                       const float* __restrict__ rho_w, const float* __restrict__ mu_b,
                       const float* __restrict__ rho_b,
                       float* __restrict__ w1, float* __restrict__ w2,
                       float* __restrict__ w4, float* __restrict__ ball){
    const int per = 31080;  // 500 + 25000 + 5000 + 580
    int idx = blockIdx.x * blockDim.x + threadIdx.x;
    if (idx >= Sn * per) return;
    int s = idx / per, j = idx % per;
    if (j < 25500){
        int g = j;  // conv1 [0,500) + conv2 [500,25500)
        float v = mu_w[g] + sp_f(rho_w[g]) * e[s*EWc + g];
        if (j < 500) w1[s*500 + j] = v;
        else         w2[s*25000 + (j - 500)] = v;
    } else if (j < 30500){
        int g = 425500 + (j - 25500);   // aff2 weights
        float v = mu_w[g] + sp_f(rho_w[g]) * e[s*EWc + g];
        w4[s*5000 + (j - 25500)] = v;
    } else {
        int k = j - 30500;
        float v = mu_b[k] + sp_f(rho_b[k]) * e[s*EWc + NWc + k];
        ball[s*580 + k] = v;
    }
}

// ---------------- K1: conv1 + ReLU + 2x2 maxpool ----------------
// h1p layout: [s][b][c(20)][y(12)][x(12)]
__global__ __launch_bounds__(256, 2) void k1_conv1(const float* __restrict__ x,
        const float* __restrict__ w1, const float* __restrict__ ball,
        float* __restrict__ h1p){
    __shared__ __align__(16) float xs[784];
    __shared__ __align__(16) float w1s[500];
    __shared__ float b1s[20];
    int bid = blockIdx.x;
    int s = bid / Bn, b = bid % Bn;
    int tid = threadIdx.x;
    for (int i = tid; i < 784; i += 256) xs[i] = x[b*784 + i];
    for (int i = tid; i < 500; i += 256) w1s[i] = w1[s*500 + i];
    if (tid < 20) b1s[tid] = ball[s*580 + tid];
    __syncthreads();
    if (tid >= 240) return;           // no further barriers below
    int c = tid / 12, y = tid % 12;   // pooled output row y, channel c

    float acc0[24], acc1[24];         // conv rows 2y and 2y+1, cols 0..23
    #pragma unroll
    for (int i = 0; i < 24; ++i){ acc0[i] = 0.f; acc1[i] = 0.f; }

    #pragma unroll
    for (int ky = 0; ky < 5; ++ky){
        float rlo[28], rhi[28];
        const float* plo = &xs[(2*y + ky) * 28];
        const float* phi = &xs[(2*y + ky + 1) * 28];
        #pragma unroll
        for (int cc = 0; cc < 28; cc += 4){
            float4 v0 = *(const float4*)(plo + cc);
            rlo[cc] = v0.x; rlo[cc+1] = v0.y; rlo[cc+2] = v0.z; rlo[cc+3] = v0.w;
            float4 v1 = *(const float4*)(phi + cc);
            rhi[cc] = v1.x; rhi[cc+1] = v1.y; rhi[cc+2] = v1.z; rhi[cc+3] = v1.w;
        }
        #pragma unroll
        for (int kx = 0; kx < 5; ++kx){
            float wv = w1s[c*25 + ky*5 + kx];
            #pragma unroll
            for (int cx = 0; cx < 24; ++cx){
                acc0[cx] = fmaf(rlo[cx + kx], wv, acc0[cx]);
                acc1[cx] = fmaf(rhi[cx + kx], wv, acc1[cx]);
            }
        }
    }
    float bias = b1s[c];
    float outv[12];
    #pragma unroll
    for (int px = 0; px < 12; ++px){
        float m = fmaxf(fmaxf(acc0[2*px], acc0[2*px+1]),
                        fmaxf(acc1[2*px], acc1[2*px+1]));
        outv[px] = fmaxf(m + bias, 0.f);
    }
    float* dst = &h1p[((s*Bn + b)*20 + c)*144 + y*12];
    #pragma unroll
    for (int px = 0; px < 12; px += 4)
        *(float4*)(dst + px) = make_float4(outv[px], outv[px+1], outv[px+2], outv[px+3]);
}

// ---------------- K2: conv2 + ReLU + 2x2 maxpool ----------------
// block = (s, group of 4 images); wave w -> image g*4+w; lane -> oc
// h2p layout: [s][b][i=oc*16+py*4+px]  (matches reference flatten)
__global__ __launch_bounds__(256, 1) void k2_conv2(const float* __restrict__ h1p,
        const float* __restrict__ w2, const float* __restrict__ ball,
        float* __restrict__ h2p){
    __shared__ __align__(16) float w2t[25000];   // [k=ic*25+kk][oc] stride 50
    __shared__ __align__(16) float in4[4*2880];  // 4 images x (20*12*12)
    __shared__ float b2s[50];
    int bid = blockIdx.x;
    int s = bid / 32, g = bid % 32;
    int tid = threadIdx.x;
    // stage weights transposed: lane-consecutive oc -> conflict-free reads later
    for (int j = tid; j < 25000; j += 256){
        int oc = j / 500, k = j % 500;
        w2t[k*50 + oc] = w2[s*25000 + j];
    }
    for (int j = tid; j < 4*2880; j += 256)
        in4[j] = h1p[(s*Bn + g*4 + (j / 2880))*2880 + (j % 2880)];
    if (tid < 50) b2s[tid] = ball[s*580 + 20 + tid];
    __syncthreads();

    int wv = tid >> 6, lane = tid & 63;
    int b = g*4 + wv;
    int oc = lane < 50 ? lane : 49;   // clamp; lanes >=50 masked at store
    const float* inp = &in4[wv * 2880];

    float acc[64];                    // conv output 8x8 (pre-pool)
    #pragma unroll
    for (int i = 0; i < 64; ++i) acc[i] = 0.f;

    #pragma unroll 1
    for (int ic = 0; ic < 20; ++ic){
        float wr[25];
        #pragma unroll
        for (int k = 0; k < 25; ++k) wr[k] = w2t[(ic*25 + k)*50 + oc];
        const float* pl = inp + ic*144;
        #pragma unroll
        for (int r = 0; r < 12; ++r){
            float row[12];
            #pragma unroll
            for (int q = 0; q < 12; q += 4){
                float4 v = *(const float4*)(pl + r*12 + q);
                row[q] = v.x; row[q+1] = v.y; row[q+2] = v.z; row[q+3] = v.w;
            }
            #pragma unroll
            for (int ky = 0; ky < 5; ++ky){
                int oy = r - ky;
                if (oy < 0 || oy > 7) continue;
                #pragma unroll
                for (int kx = 0; kx < 5; ++kx){
                    float wgt = wr[ky*5 + kx];
                    #pragma unroll
                    for (int ox = 0; ox < 8; ++ox)
                        acc[oy*8 + ox] = fmaf(row[ox + kx], wgt, acc[oy*8 + ox]);
                }
            }
        }
    }
    float bias = b2s[oc];
    if (lane < 50){
        float* dst = &h2p[(s*Bn + b)*800 + oc*16];
        #pragma unroll
        for (int py = 0; py < 4; ++py){
            float4 o4;
            float* po = (float*)&o4;
            #pragma unroll
            for (int px = 0; px < 4; ++px){
                float m = fmaxf(fmaxf(acc[(2*py)*8 + 2*px],     acc[(2*py)*8 + 2*px + 1]),
                                fmaxf(acc[(2*py+1)*8 + 2*px],   acc[(2*py+1)*8 + 2*px + 1]));
                po[px] = fmaxf(m + bias, 0.f);
            }
            *(float4*)(dst + py*4) = o4;
        }
    }
}

// ---------------- K3: aff1 GEMM (per s: 128x500x800), w3 generated on the fly ----------------
// h3 layout: [s][b][o(500)]
__global__ __launch_bounds__(256) void k3_aff1(const float* __restrict__ h2p,
        const float* __restrict__ e, const float* __restrict__ mu_w,
        const float* __restrict__ rho_w, const float* __restrict__ ball,
        float* __restrict__ h3){
    __shared__ __align__(16) float As[32*132];   // [k][b] padded stride 132
    __shared__ __align__(16) float Wsh[32*68];   // [k][o] padded stride 68
    int bid = blockIdx.x;
    int s = bid / 8, nt = bid % 8;
    int o0 = nt * 64;
    int ow = 500 - o0; if (ow > 64) ow = 64;     // last tile = 52
    int tid = threadIdx.x;
    int ty = tid >> 4, tx = tid & 15;            // 16x16 threads, 8x4 micro-tile

    float acc[8][4];
    #pragma unroll
    for (int r = 0; r < 8; ++r)
        #pragma unroll
        for (int c = 0; c < 4; ++c) acc[r][c] = 0.f;

    const float* mu3  = mu_w  + 25500;
    const float* rho3 = rho_w + 25500;
    const float* e3   = e + s*EWc + 25500;

    #pragma unroll 1
    for (int k0 = 0; k0 < 800; k0 += 32){
        #pragma unroll
        for (int it = 0; it < 16; ++it){         // 4096 A elements
            int j = tid + it*256;
            int bb = j >> 5, kk = j & 31;
            As[kk*132 + bb] = h2p[(s*Bn + bb)*800 + k0 + kk];
        }
        for (int j = tid; j < ow*32; j += 256){  // gen W tile on the fly
            int o = j >> 5, kk = j & 31;
            int gg = (o0 + o)*800 + k0 + kk;
            Wsh[kk*68 + o] = mu3[gg] + sp_f(rho3[gg]) * e3[gg];
        }
        __syncthreads();
        #pragma unroll
        for (int kk = 0; kk < 32; ++kk){
            float4 a0 = *(const float4*)&As[kk*132 + ty*8];
            float4 a1 = *(const float4*)&As[kk*132 + ty*8 + 4];
            float4 b0 = *(const float4*)&Wsh[kk*68 + tx*4];
            float av[8] = {a0.x,a0.y,a0.z,a0.w,a1.x,a1.y,a1.z,a1.w};
            float bv[4] = {b0.x,b0.y,b0.z,b0.w};
            #pragma unroll
            for (int r = 0; r < 8; ++r)
                #pragma unroll
                for (int c = 0; c < 4; ++c)
                    acc[r][c] = fmaf(av[r], bv[c], acc[r][c]);
        }
        __syncthreads();
    }
    #pragma unroll
    for (int c = 0; c < 4; ++c){
        int o = o0 + tx*4 + c;
        if (o < 500){
            float bias = ball[s*580 + 70 + o];
            #pragma unroll
            for (int r = 0; r < 8; ++r){
                int b = ty*8 + r;
                h3[(s*Bn + b)*500 + o] = fmaxf(acc[r][c] + bias, 0.f);
            }
        }
    }
}

// ---------------- K4a: aff2 + log_softmax per (s,b) ----------------
// lsw layout: [p=s*128+b][10]
__global__ __launch_bounds__(256) void k4a(const float* __restrict__ h3,
        const float* __restrict__ w4, const float* __restrict__ ball,
        float* __restrict__ lsw){
    int wv = threadIdx.x >> 6, lane = threadIdx.x & 63;
    int p = blockIdx.x*4 + wv;         // < 12800
    int s = p / Bn;
    const float* hp = &h3[p*500];
    const float* wp = &w4[s*5000];
    float part[10];
    #pragma unroll
    for (int o = 0; o < 10; ++o) part[o] = 0.f;
    for (int i = lane; i < 500; i += 64){
        float hv = hp[i];
        #pragma unroll
        for (int o = 0; o < 10; ++o)
            part[o] = fmaf(hv, wp[o*500 + i], part[o]);
    }
    #pragma unroll
    for (int o = 0; o < 10; ++o){
        #pragma unroll
        for (int d = 1; d < 64; d <<= 1)
            part[o] += __shfl_xor(part[o], d);
    }
    float v[10]; float m = -INFINITY;
    #pragma unroll
    for (int o = 0; o < 10; ++o){
        v[o] = part[o] + ball[s*580 + 570 + o];
        m = fmaxf(m, v[o]);
    }
    float sum = 0.f;
    #pragma unroll
    for (int o = 0; o < 10; ++o) sum += __expf(v[o] - m);
    float lse = m + __logf(sum);
    if (lane == 0){
        #pragma unroll
        for (int o = 0; o < 10; ++o) lsw[p*10 + o] = v[o] - lse;
    }
}

// ---------------- K4b: mean over samples ----------------
__global__ void k4b(const float* __restrict__ lsw, float* __restrict__ outp){
    int j = blockIdx.x * blockDim.x + threadIdx.x;
    if (j >= Bn*10) return;
    int b = j / 10, o = j % 10;
    float acc = 0.f;
    for (int s2 = 0; s2 < Sn; ++s2) acc += lsw[(s2*Bn + b)*10 + o];
    outp[j] = acc * (1.f / (float)Sn);
}

extern "C" void kernel_launch(void* const* d_in, const int* in_sizes, int n_in,
                              void* d_out, int out_size, void* d_ws, size_t ws_size,
                              hipStream_t stream){
    const float* x     = (const float*)d_in[0];
    const float* e     = (const float*)d_in[1];
    const float* mu_w  = (const float*)d_in[2];
    const float* rho_w = (const float*)d_in[3];
    const float* mu_b  = (const float*)d_in[4];
    const float* rho_b = (const float*)d_in[5];
    float* ws   = (float*)d_ws;
    float* h1p  = ws;                      // 36,864,000 floats (147.5 MB)
    float* h2p  = h1p + 36864000;          // 10,240,000
    float* h3   = h2p + 10240000;          //  6,400,000
    float* w1   = h3  + 6400000;           //     50,000
    float* w2   = w1  + 50000;             //  2,500,000
    float* w4   = w2  + 2500000;           //    500,000
    float* ball = w4  + 500000;            //     58,000
    float* lsw  = ball + 58000;            //    128,000  (total ~227 MB)
    float* outp = (float*)d_out;

    k0_gen  <<<(Sn*31080 + 255)/256, 256, 0, stream>>>(e, mu_w, rho_w, mu_b, rho_b, w1, w2, w4, ball);
    k1_conv1<<<Sn*Bn, 256, 0, stream>>>(x, w1, ball, h1p);
    k2_conv2<<<Sn*32, 256, 0, stream>>>(h1p, w2, ball, h2p);
    k3_aff1 <<<Sn*8, 256, 0, stream>>>(h2p, e, mu_w, rho_w, ball, h3);
    k4a     <<<3200, 256, 0, stream>>>(h3, w4, ball, lsw);
    k4b     <<<(Bn*10 + 255)/256, 256, 0, stream>>>(lsw, outp);
}

// Round 3
// 616.990 us; speedup vs baseline: 2.2381x; 2.2381x over previous
//
#include <hip/hip_runtime.h>
#include <math.h>

#define Sn 100
#define Bn 128
#define NWc 430500
#define EWc 431080   // NW + NB

typedef __attribute__((ext_vector_type(8)))  short bhalf8;
typedef __attribute__((ext_vector_type(16))) float fx16;

__device__ __forceinline__ float sp_f(float r){
    return fmaxf(r, 0.f) + log1pf(__expf(-fabsf(r)));   // stable softplus
}
__device__ __forceinline__ ushort bfr(float f){          // fp32 -> bf16 RNE
    union { float f; uint u; } c; c.f = f;
    uint r = (c.u + 0x7FFFu + ((c.u >> 16) & 1u)) >> 16;
    return (ushort)r;
}

// ---------------- K0: materialize params ----------------
// w1 fp32 [s][oc20*25], w2r bf16 [s][kk25][oc64][ic32] (zero-padded by memset),
// w4 fp32 [s][10*500], ball fp32 [s][580]
__global__ void k0_gen(const float* __restrict__ e, const float* __restrict__ mu_w,
                       const float* __restrict__ rho_w, const float* __restrict__ mu_b,
                       const float* __restrict__ rho_b,
                       float* __restrict__ w1, ushort* __restrict__ w2r,
                       float* __restrict__ w4, float* __restrict__ ball){
    const int per = 31080;  // 500 + 25000 + 5000 + 580
    int idx = blockIdx.x * blockDim.x + threadIdx.x;
    if (idx >= Sn * per) return;
    int s = idx / per, j = idx % per;
    if (j < 500){
        float v = mu_w[j] + sp_f(rho_w[j]) * e[s*EWc + j];
        w1[s*500 + j] = v;
    } else if (j < 25500){
        int g = j;                       // global weight index
        float v = mu_w[g] + sp_f(rho_w[g]) * e[s*EWc + g];
        int j2 = j - 500;
        int oc = j2 / 500, rem = j2 % 500;
        int ic = rem / 25, kk = rem % 25;
        w2r[s*51200 + (kk*64 + oc)*32 + ic] = bfr(v);
    } else if (j < 30500){
        int g = 425500 + (j - 25500);    // aff2 weights
        float v = mu_w[g] + sp_f(rho_w[g]) * e[s*EWc + g];
        w4[s*5000 + (j - 25500)] = v;
    } else {
        int k = j - 30500;
        float v = mu_b[k] + sp_f(rho_b[k]) * e[s*EWc + NWc + k];
        ball[s*580 + k] = v;
    }
}

// ---------------- K1: conv1 + ReLU + 2x2 maxpool ----------------
// h1p bf16 layout: [s][b][pix=y*12+x][ic20]  (channel-last for MFMA k2)
__global__ __launch_bounds__(256, 2) void k1_conv1(const float* __restrict__ x,
        const float* __restrict__ w1, const float* __restrict__ ball,
        ushort* __restrict__ h1p){
    __shared__ __align__(16) float xs[784];
    __shared__ __align__(16) float w1s[500];
    __shared__ float b1s[20];
    __shared__ __align__(16) ushort ots[2880];   // [pix144][ic20] bf16
    int bid = blockIdx.x;
    int s = bid / Bn, b = bid % Bn;
    int tid = threadIdx.x;
    for (int i = tid; i < 784; i += 256) xs[i] = x[b*784 + i];
    for (int i = tid; i < 500; i += 256) w1s[i] = w1[s*500 + i];
    if (tid < 20) b1s[tid] = ball[s*580 + tid];
    __syncthreads();
    if (tid < 240){
        int c = tid / 12, y = tid % 12;   // pooled row y, channel c

        float acc0[24], acc1[24];
        #pragma unroll
        for (int i = 0; i < 24; ++i){ acc0[i] = 0.f; acc1[i] = 0.f; }

        #pragma unroll
        for (int ky = 0; ky < 5; ++ky){
            float rlo[28], rhi[28];
            const float* plo = &xs[(2*y + ky) * 28];
            const float* phi = &xs[(2*y + ky + 1) * 28];
            #pragma unroll
            for (int cc = 0; cc < 28; cc += 4){
                float4 v0 = *(const float4*)(plo + cc);
                rlo[cc] = v0.x; rlo[cc+1] = v0.y; rlo[cc+2] = v0.z; rlo[cc+3] = v0.w;
                float4 v1 = *(const float4*)(phi + cc);
                rhi[cc] = v1.x; rhi[cc+1] = v1.y; rhi[cc+2] = v1.z; rhi[cc+3] = v1.w;
            }
            #pragma unroll
            for (int kx = 0; kx < 5; ++kx){
                float wv = w1s[c*25 + ky*5 + kx];
                #pragma unroll
                for (int cx = 0; cx < 24; ++cx){
                    acc0[cx] = fmaf(rlo[cx + kx], wv, acc0[cx]);
                    acc1[cx] = fmaf(rhi[cx + kx], wv, acc1[cx]);
                }
            }
        }
        float bias = b1s[c];
        #pragma unroll
        for (int px = 0; px < 12; ++px){
            float m = fmaxf(fmaxf(acc0[2*px], acc0[2*px+1]),
                            fmaxf(acc1[2*px], acc1[2*px+1]));
            ots[(y*12 + px)*20 + c] = bfr(fmaxf(m + bias, 0.f));
        }
    }
    __syncthreads();
    const uint* o32 = (const uint*)ots;
    uint* g32 = (uint*)(h1p + (s*Bn + b)*2880);
    for (int j = tid; j < 1440; j += 256) g32[j] = o32[j];
}

// ---------------- K2: conv2 + ReLU + pool via MFMA 32x32x16 bf16 ----------------
// 25 per-(ky,kx) GEMMs over ic (K=20 pad 32); wave = one image (M=64 pix, N=64 oc)
// h2p bf16 [s][b][i=oc*16+py*4+px]
#define ICS 40   // u16 stride per pixel in LDS (bank-stagger pad)
__global__ __launch_bounds__(256, 3) void k2_mfma(const ushort* __restrict__ h1p,
        const ushort* __restrict__ w2r, const float* __restrict__ ball,
        ushort* __restrict__ h2p){
    __shared__ __align__(16) ushort img[4*144*ICS];   // 46080 B
    __shared__ __align__(16) ushort Bs[64*ICS];       //  5120 B
    int bid = blockIdx.x;
    int s = bid >> 5, g = bid & 31;
    int tid = threadIdx.x;
    // stage 4 images: global [im][pix][20] -> LDS [im][pix][ICS] (cols 0..19)
    const uint* g32 = (const uint*)(h1p + (size_t)(s*Bn + g*4)*2880);
    uint* l32 = (uint*)img;
    for (int j = tid; j < 5760; j += 256){            // 4*1440 u32
        int im = j / 1440, r = j - im*1440;
        int p = r / 10, u = r - p*10;
        l32[im*2880 + p*20 + u] = g32[j];
    }
    for (int j = tid; j < 3456; j += 256){            // zero pad ic 20..31
        int im = j / 864, r = j - im*864;
        int p = r / 6, u = 10 + (r - p*6);
        l32[im*2880 + p*20 + u] = 0u;
    }
    int wv = tid >> 6, l = tid & 63;
    int l31 = l & 31, q = l >> 5;
    const ushort* imgw = img + wv*5760;
    int pixb0 = ((l31      ) >> 3)*12 + (l31 & 7);    // m-tile 0 pixel base
    int pixb1 = ((l31 + 32 ) >> 3)*12 + (l31 & 7);    // m-tile 1
    fx16 acc00 = (fx16)0.f, acc01 = (fx16)0.f, acc10 = (fx16)0.f, acc11 = (fx16)0.f;

    for (int kk = 0; kk < 25; ++kk){
        __syncthreads();
        {   // stage [oc64][ic32] = 2048 ushorts = 256 uint4: one per thread
            uint4 v = ((const uint4*)(w2r + (size_t)(s*25 + kk)*2048))[tid];
            *(uint4*)&Bs[(tid>>2)*ICS + (tid&3)*8] = v;
        }
        __syncthreads();
        int ky = kk / 5, kx = kk - ky*5;
        int poff = ky*12 + kx;
        #pragma unroll
        for (int ics = 0; ics < 2; ++ics){
            bhalf8 a0 = *(const bhalf8*)(imgw + (pixb0 + poff)*ICS + ics*16 + q*8);
            bhalf8 a1 = *(const bhalf8*)(imgw + (pixb1 + poff)*ICS + ics*16 + q*8);
            bhalf8 b0 = *(const bhalf8*)(Bs + (l31     )*ICS + ics*16 + q*8);
            bhalf8 b1 = *(const bhalf8*)(Bs + (l31 + 32)*ICS + ics*16 + q*8);
            acc00 = __builtin_amdgcn_mfma_f32_32x32x16_bf16(a0, b0, acc00, 0, 0, 0);
            acc01 = __builtin_amdgcn_mfma_f32_32x32x16_bf16(a0, b1, acc01, 0, 0, 0);
            acc10 = __builtin_amdgcn_mfma_f32_32x32x16_bf16(a1, b0, acc10, 0, 0, 0);
            acc11 = __builtin_amdgcn_mfma_f32_32x32x16_bf16(a1, b1, acc11, 0, 0, 0);
        }
    }
    // epilogue: intra-lane 2x2 maxpool, bias+relu, bf16 store
    int b = g*4 + wv;
    ushort* dst = h2p + (size_t)(s*Bn + b)*800;
    #pragma unroll
    for (int nt = 0; nt < 2; ++nt){
        int oc = nt*32 + l31;
        if (oc >= 50) continue;
        float bias = ball[s*580 + 20 + oc];
        #pragma unroll
        for (int mt = 0; mt < 2; ++mt){
            fx16 a;
            if (nt == 0) a = mt ? acc10 : acc00;
            else         a = mt ? acc11 : acc01;
            #pragma unroll
            for (int gp = 0; gp < 2; ++gp){
                // rows: g=2gp -> regs 8gp+{0,1,4,5} ; pairs with 8gp+{2,3,6,7}
                float p0 = fmaxf(fmaxf(a[8*gp+0], a[8*gp+1]), fmaxf(a[8*gp+4], a[8*gp+5]));
                float p1 = fmaxf(fmaxf(a[8*gp+2], a[8*gp+3]), fmaxf(a[8*gp+6], a[8*gp+7]));
                p0 = fmaxf(p0 + bias, 0.f);
                p1 = fmaxf(p1 + bias, 0.f);
                int py = mt*2 + gp, px0 = 2*q;
                uint pk = (uint)bfr(p0) | ((uint)bfr(p1) << 16);
                *(uint*)(dst + oc*16 + py*4 + px0) = pk;
            }
        }
    }
}

// ---------------- K3: aff1 via MFMA (per s: 128 x 512pad x 800), B on the fly ----------------
// h3 fp32 [s][b][o500]
__global__ __launch_bounds__(256, 4) void k3_mfma(const ushort* __restrict__ h2p,
        const float* __restrict__ e, const float* __restrict__ mu_w,
        const float* __restrict__ rho_w, const float* __restrict__ ball,
        float* __restrict__ h3){
    __shared__ __align__(16) ushort As[128*ICS];   // 10240 B
    __shared__ __align__(16) ushort Bsh[64*ICS];   //  5120 B
    int bid = blockIdx.x;
    int s = bid >> 3, nblk = bid & 7;
    int o0 = nblk * 64;
    int tid = threadIdx.x;
    const float* mu3  = mu_w  + 25500;
    const float* rho3 = rho_w + 25500;
    const float* e3   = e + (size_t)s*EWc + 25500;
    int wv = tid >> 6, l = tid & 63, l31 = l & 31, q = l >> 5;
    int wm = wv >> 1, wn = wv & 1;
    fx16 acc0 = (fx16)0.f, acc1 = (fx16)0.f;
    int sb = tid >> 1, sh = tid & 1;        // A staging: row, 16-el half
    int so = tid >> 2, sk = (tid & 3)*8;    // B staging: o-offset, k-offset
    int og = o0 + so;

    for (int k0 = 0; k0 < 800; k0 += 32){
        __syncthreads();
        {   // A: h2p bf16 rows -> LDS
            const uint4* src = (const uint4*)(h2p + (size_t)(s*Bn + sb)*800 + k0 + sh*16);
            uint4 v0 = src[0], v1 = src[1];
            *(uint4*)&As[sb*ICS + sh*16]     = v0;
            *(uint4*)&As[sb*ICS + sh*16 + 8] = v1;
        }
        {   // B: softplus-gen 8 elements
            ushort tmp[8];
            if (og < 500){
                int gg = og*800 + k0 + sk;
                #pragma unroll
                for (int j = 0; j < 8; ++j){
                    float v = mu3[gg+j] + sp_f(rho3[gg+j]) * e3[gg+j];
                    tmp[j] = bfr(v);
                }
            } else {
                #pragma unroll
                for (int j = 0; j < 8; ++j) tmp[j] = 0;
            }
            *(uint4*)&Bsh[so*ICS + sk] = *(const uint4*)tmp;
        }
        __syncthreads();
        #pragma unroll
        for (int ks = 0; ks < 2; ++ks){
            bhalf8 a0 = *(const bhalf8*)&As[(wm*64      + l31)*ICS + ks*16 + q*8];
            bhalf8 a1 = *(const bhalf8*)&As[(wm*64 + 32 + l31)*ICS + ks*16 + q*8];
            bhalf8 bb = *(const bhalf8*)&Bsh[(wn*32 + l31)*ICS + ks*16 + q*8];
            acc0 = __builtin_amdgcn_mfma_f32_32x32x16_bf16(a0, bb, acc0, 0, 0, 0);
            acc1 = __builtin_amdgcn_mfma_f32_32x32x16_bf16(a1, bb, acc1, 0, 0, 0);
        }
    }
    int o = o0 + wn*32 + l31;
    if (o < 500){
        float bias = ball[s*580 + 70 + o];
        #pragma unroll
        for (int mt = 0; mt < 2; ++mt){
            fx16 a = mt ? acc1 : acc0;
            #pragma unroll
            for (int reg = 0; reg < 16; ++reg){
                int row = (reg & 3) + 8*(reg >> 2) + 4*q;
                int b = wm*64 + mt*32 + row;
                h3[(size_t)(s*Bn + b)*500 + o] = fmaxf(a[reg] + bias, 0.f);
            }
        }
    }
}

// ---------------- K4a: aff2 + log_softmax per (s,b) ----------------
__global__ __launch_bounds__(256) void k4a(const float* __restrict__ h3,
        const float* __restrict__ w4, const float* __restrict__ ball,
        float* __restrict__ lsw){
    int wv = threadIdx.x >> 6, lane = threadIdx.x & 63;
    int p = blockIdx.x*4 + wv;
    int s = p / Bn;
    const float* hp = &h3[(size_t)p*500];
    const float* wp = &w4[(size_t)s*5000];
    float part[10];
    #pragma unroll
    for (int o = 0; o < 10; ++o) part[o] = 0.f;
    for (int i = lane; i < 500; i += 64){
        float hv = hp[i];
        #pragma unroll
        for (int o = 0; o < 10; ++o)
            part[o] = fmaf(hv, wp[o*500 + i], part[o]);
    }
    #pragma unroll
    for (int o = 0; o < 10; ++o){
        #pragma unroll
        for (int d = 1; d < 64; d <<= 1)
            part[o] += __shfl_xor(part[o], d);
    }
    float v[10]; float m = -INFINITY;
    #pragma unroll
    for (int o = 0; o < 10; ++o){
        v[o] = part[o] + ball[s*580 + 570 + o];
        m = fmaxf(m, v[o]);
    }
    float sum = 0.f;
    #pragma unroll
    for (int o = 0; o < 10; ++o) sum += __expf(v[o] - m);
    float lse = m + __logf(sum);
    if (lane == 0){
        #pragma unroll
        for (int o = 0; o < 10; ++o) lsw[p*10 + o] = v[o] - lse;
    }
}

// ---------------- K4b: mean over samples ----------------
__global__ void k4b(const float* __restrict__ lsw, float* __restrict__ outp){
    int j = blockIdx.x * blockDim.x + threadIdx.x;
    if (j >= Bn*10) return;
    int b = j / 10, o = j % 10;
    float acc = 0.f;
    for (int s2 = 0; s2 < Sn; ++s2) acc += lsw[(s2*Bn + b)*10 + o];
    outp[j] = acc * (1.f / (float)Sn);
}

extern "C" void kernel_launch(void* const* d_in, const int* in_sizes, int n_in,
                              void* d_out, int out_size, void* d_ws, size_t ws_size,
                              hipStream_t stream){
    const float* x     = (const float*)d_in[0];
    const float* e     = (const float*)d_in[1];
    const float* mu_w  = (const float*)d_in[2];
    const float* rho_w = (const float*)d_in[3];
    const float* mu_b  = (const float*)d_in[4];
    const float* rho_b = (const float*)d_in[5];
    float* ws   = (float*)d_ws;
    float* w1   = ws;                       //     50,000 f
    float* w4   = w1 + 50000;               //    500,000 f
    float* ball = w4 + 500000;              //     58,000 f
    float* h3   = ball + 58000;             //  6,400,000 f
    float* lsw  = h3 + 6400000;             //    128,000 f
    ushort* h1p = (ushort*)(lsw + 128000);  // 36,864,000 u16
    ushort* h2p = h1p + 36864000;           // 10,240,000 u16
    ushort* w2r = h2p + 10240000;           //  5,120,000 u16
    float* outp = (float*)d_out;

    hipMemsetAsync(w2r, 0, (size_t)Sn*51200*2, stream);
    k0_gen  <<<(Sn*31080 + 255)/256, 256, 0, stream>>>(e, mu_w, rho_w, mu_b, rho_b, w1, w2r, w4, ball);
    k1_conv1<<<Sn*Bn, 256, 0, stream>>>(x, w1, ball, h1p);
    k2_mfma <<<Sn*32, 256, 0, stream>>>(h1p, w2r, ball, h2p);
    k3_mfma <<<Sn*8, 256, 0, stream>>>(h2p, e, mu_w, rho_w, ball, h3);
    k4a     <<<3200, 256, 0, stream>>>(h3, w4, ball, lsw);
    k4b     <<<(Bn*10 + 255)/256, 256, 0, stream>>>(lsw, outp);
}

// Round 4
// 566.478 us; speedup vs baseline: 2.4376x; 1.0892x over previous
//
#include <hip/hip_runtime.h>
#include <math.h>

#define Sn 100
#define Bn 128
#define NWc 430500
#define EWc 431080   // NW + NB

typedef __attribute__((ext_vector_type(8)))  short bhalf8;
typedef __attribute__((ext_vector_type(16))) float fx16;

__device__ __forceinline__ float sp_f(float r){
    return fmaxf(r, 0.f) + log1pf(__expf(-fabsf(r)));   // stable softplus
}
__device__ __forceinline__ ushort bfr(float f){          // fp32 -> bf16 RNE
    union { float f; uint u; } c; c.f = f;
    uint r = (c.u + 0x7FFFu + ((c.u >> 16) & 1u)) >> 16;
    return (ushort)r;
}

// ---------------- K00: softplus(rho) once for ALL params (shared across s) ----------------
__global__ void k00_sp(const float* __restrict__ rho_w, const float* __restrict__ rho_b,
                       float* __restrict__ sp_all){
    int i = blockIdx.x * blockDim.x + threadIdx.x;
    if (i < NWc)      sp_all[i] = sp_f(rho_w[i]);
    else if (i < EWc) sp_all[i] = sp_f(rho_b[i - NWc]);
}

// ---------------- K0: materialize params ----------------
// w1 fp32 [s][oc20*25], w2r bf16 [s][kk25][oc64][ic32] (zero-padded by memset),
// w4 fp32 [s][10*500], ball fp32 [s][580]
__global__ void k0_gen(const float* __restrict__ e, const float* __restrict__ mu_w,
                       const float* __restrict__ sp_all, const float* __restrict__ mu_b,
                       float* __restrict__ w1, ushort* __restrict__ w2r,
                       float* __restrict__ w4, float* __restrict__ ball){
    const int per = 31080;  // 500 + 25000 + 5000 + 580
    int idx = blockIdx.x * blockDim.x + threadIdx.x;
    if (idx >= Sn * per) return;
    int s = idx / per, j = idx % per;
    if (j < 500){
        float v = fmaf(sp_all[j], e[s*EWc + j], mu_w[j]);
        w1[s*500 + j] = v;
    } else if (j < 25500){
        int g = j;
        float v = fmaf(sp_all[g], e[s*EWc + g], mu_w[g]);
        int j2 = j - 500;
        int oc = j2 / 500, rem = j2 % 500;
        int ic = rem / 25, kk = rem % 25;
        w2r[s*51200 + (kk*64 + oc)*32 + ic] = bfr(v);
    } else if (j < 30500){
        int g = 425500 + (j - 25500);
        float v = fmaf(sp_all[g], e[s*EWc + g], mu_w[g]);
        w4[s*5000 + (j - 25500)] = v;
    } else {
        int k = j - 30500;
        float v = fmaf(sp_all[NWc + k], e[s*EWc + NWc + k], mu_b[k]);
        ball[s*580 + k] = v;
    }
}

// ---------------- K1: conv1 + ReLU + 2x2 maxpool ----------------
// h1p bf16 layout: [s][b][pix=y*12+x][ic20]  (channel-last for MFMA k2)
__global__ __launch_bounds__(256, 2) void k1_conv1(const float* __restrict__ x,
        const float* __restrict__ w1, const float* __restrict__ ball,
        ushort* __restrict__ h1p){
    __shared__ __align__(16) float xs[784];
    __shared__ __align__(16) float w1s[500];
    __shared__ float b1s[20];
    __shared__ __align__(16) ushort ots[2880];   // [pix144][ic20] bf16
    int bid = blockIdx.x;
    int s = bid / Bn, b = bid % Bn;
    int tid = threadIdx.x;
    for (int i = tid; i < 784; i += 256) xs[i] = x[b*784 + i];
    for (int i = tid; i < 500; i += 256) w1s[i] = w1[s*500 + i];
    if (tid < 20) b1s[tid] = ball[s*580 + tid];
    __syncthreads();
    if (tid < 240){
        int c = tid / 12, y = tid % 12;   // pooled row y, channel c

        float acc0[24], acc1[24];
        #pragma unroll
        for (int i = 0; i < 24; ++i){ acc0[i] = 0.f; acc1[i] = 0.f; }

        #pragma unroll
        for (int ky = 0; ky < 5; ++ky){
            float rlo[28], rhi[28];
            const float* plo = &xs[(2*y + ky) * 28];
            const float* phi = &xs[(2*y + ky + 1) * 28];
            #pragma unroll
            for (int cc = 0; cc < 28; cc += 4){
                float4 v0 = *(const float4*)(plo + cc);
                rlo[cc] = v0.x; rlo[cc+1] = v0.y; rlo[cc+2] = v0.z; rlo[cc+3] = v0.w;
                float4 v1 = *(const float4*)(phi + cc);
                rhi[cc] = v1.x; rhi[cc+1] = v1.y; rhi[cc+2] = v1.z; rhi[cc+3] = v1.w;
            }
            #pragma unroll
            for (int kx = 0; kx < 5; ++kx){
                float wv = w1s[c*25 + ky*5 + kx];
                #pragma unroll
                for (int cx = 0; cx < 24; ++cx){
                    acc0[cx] = fmaf(rlo[cx + kx], wv, acc0[cx]);
                    acc1[cx] = fmaf(rhi[cx + kx], wv, acc1[cx]);
                }
            }
        }
        float bias = b1s[c];
        #pragma unroll
        for (int px = 0; px < 12; ++px){
            float m = fmaxf(fmaxf(acc0[2*px], acc0[2*px+1]),
                            fmaxf(acc1[2*px], acc1[2*px+1]));
            ots[(y*12 + px)*20 + c] = bfr(fmaxf(m + bias, 0.f));
        }
    }
    __syncthreads();
    const uint* o32 = (const uint*)ots;
    uint* g32 = (uint*)(h1p + (s*Bn + b)*2880);
    for (int j = tid; j < 1440; j += 256) g32[j] = o32[j];
}

// ---------------- K2: conv2 + ReLU + pool via MFMA 32x32x16 bf16 ----------------
// 25 per-(ky,kx) GEMMs over ic (K=20 pad 32); wave = one image (M=64 pix, N=64 oc)
// h2p bf16 [s][b][i=oc*16+py*4+px]
#define ICS 40   // u16 stride per pixel in LDS (bank-stagger pad)
__global__ __launch_bounds__(256, 3) void k2_mfma(const ushort* __restrict__ h1p,
        const ushort* __restrict__ w2r, const float* __restrict__ ball,
        ushort* __restrict__ h2p){
    __shared__ __align__(16) ushort img[4*144*ICS];   // 46080 B
    __shared__ __align__(16) ushort Bs[64*ICS];       //  5120 B
    int bid = blockIdx.x;
    int s = bid >> 5, g = bid & 31;
    int tid = threadIdx.x;
    // stage 4 images: global [im][pix][20] -> LDS [im][pix][ICS] (cols 0..19)
    const uint* g32 = (const uint*)(h1p + (size_t)(s*Bn + g*4)*2880);
    uint* l32 = (uint*)img;
    for (int j = tid; j < 5760; j += 256){            // 4*1440 u32
        int im = j / 1440, r = j - im*1440;
        int p = r / 10, u = r - p*10;
        l32[im*2880 + p*20 + u] = g32[j];
    }
    for (int j = tid; j < 3456; j += 256){            // zero pad ic 20..31
        int im = j / 864, r = j - im*864;
        int p = r / 6, u = 10 + (r - p*6);
        l32[im*2880 + p*20 + u] = 0u;
    }
    int wv = tid >> 6, l = tid & 63;
    int l31 = l & 31, q = l >> 5;
    const ushort* imgw = img + wv*5760;
    int pixb0 = ((l31      ) >> 3)*12 + (l31 & 7);    // m-tile 0 pixel base
    int pixb1 = ((l31 + 32 ) >> 3)*12 + (l31 & 7);    // m-tile 1
    fx16 acc00 = (fx16)0.f, acc01 = (fx16)0.f, acc10 = (fx16)0.f, acc11 = (fx16)0.f;

    for (int kk = 0; kk < 25; ++kk){
        __syncthreads();
        {   // stage [oc64][ic32] = 2048 ushorts = 256 uint4: one per thread
            uint4 v = ((const uint4*)(w2r + (size_t)(s*25 + kk)*2048))[tid];
            *(uint4*)&Bs[(tid>>2)*ICS + (tid&3)*8] = v;
        }
        __syncthreads();
        int ky = kk / 5, kx = kk - ky*5;
        int poff = ky*12 + kx;
        #pragma unroll
        for (int ics = 0; ics < 2; ++ics){
            bhalf8 a0 = *(const bhalf8*)(imgw + (pixb0 + poff)*ICS + ics*16 + q*8);
            bhalf8 a1 = *(const bhalf8*)(imgw + (pixb1 + poff)*ICS + ics*16 + q*8);
            bhalf8 b0 = *(const bhalf8*)(Bs + (l31     )*ICS + ics*16 + q*8);
            bhalf8 b1 = *(const bhalf8*)(Bs + (l31 + 32)*ICS + ics*16 + q*8);
            acc00 = __builtin_amdgcn_mfma_f32_32x32x16_bf16(a0, b0, acc00, 0, 0, 0);
            acc01 = __builtin_amdgcn_mfma_f32_32x32x16_bf16(a0, b1, acc01, 0, 0, 0);
            acc10 = __builtin_amdgcn_mfma_f32_32x32x16_bf16(a1, b0, acc10, 0, 0, 0);
            acc11 = __builtin_amdgcn_mfma_f32_32x32x16_bf16(a1, b1, acc11, 0, 0, 0);
        }
    }
    // epilogue: intra-lane 2x2 maxpool, bias+relu, bf16 store
    int b = g*4 + wv;
    ushort* dst = h2p + (size_t)(s*Bn + b)*800;
    #pragma unroll
    for (int nt = 0; nt < 2; ++nt){
        int oc = nt*32 + l31;
        if (oc >= 50) continue;
        float bias = ball[s*580 + 20 + oc];
        #pragma unroll
        for (int mt = 0; mt < 2; ++mt){
            fx16 a;
            if (nt == 0) a = mt ? acc10 : acc00;
            else         a = mt ? acc11 : acc01;
            #pragma unroll
            for (int gp = 0; gp < 2; ++gp){
                float p0 = fmaxf(fmaxf(a[8*gp+0], a[8*gp+1]), fmaxf(a[8*gp+4], a[8*gp+5]));
                float p1 = fmaxf(fmaxf(a[8*gp+2], a[8*gp+3]), fmaxf(a[8*gp+6], a[8*gp+7]));
                p0 = fmaxf(p0 + bias, 0.f);
                p1 = fmaxf(p1 + bias, 0.f);
                int py = mt*2 + gp, px0 = 2*q;
                uint pk = (uint)bfr(p0) | ((uint)bfr(p1) << 16);
                *(uint*)(dst + oc*16 + py*4 + px0) = pk;
            }
        }
    }
}

// ---------------- K3: aff1 via MFMA (per s: 128 x 512pad x 800) ----------------
// B = mu3 + sp3*e3 on the fly (sp3 precomputed); register double-buffered staging.
// h3 fp32 [s][b][o500]
__global__ __launch_bounds__(256) void k3_mfma(const ushort* __restrict__ h2p,
        const float* __restrict__ e, const float* __restrict__ mu_w,
        const float* __restrict__ sp_all, const float* __restrict__ ball,
        float* __restrict__ h3){
    __shared__ __align__(16) ushort As[128*ICS];   // 10240 B
    __shared__ __align__(16) ushort Bsh[64*ICS];   //  5120 B
    int bid = blockIdx.x;
    int s = bid >> 3, nblk = bid & 7;
    int o0 = nblk * 64;
    int tid = threadIdx.x;
    int wv = tid >> 6, l = tid & 63, l31 = l & 31, q = l >> 5;
    int wm = wv >> 1, wn = wv & 1;
    fx16 acc0 = (fx16)0.f, acc1 = (fx16)0.f;
    int sb = tid >> 1, sh = tid & 1;        // A staging: row, 16-el half
    int so = tid >> 2, sk = (tid & 3)*8;    // B staging: o-offset, k-offset
    int og = o0 + so;
    bool bvalid = og < 500;
    const float* mp = mu_w   + 25500 + og*800 + sk;
    const float* pp = sp_all + 25500 + og*800 + sk;
    const float* ep = e + (size_t)s*EWc + 25500 + og*800 + sk;
    const ushort* ap = h2p + (size_t)(s*Bn + sb)*800 + sh*16;

    uint4 ar0, ar1;
    float4 mva, mvb, sva, svb, eva, evb;
    // prefetch tile 0
    ar0 = ((const uint4*)ap)[0]; ar1 = ((const uint4*)ap)[1];
    if (bvalid){
        mva = *(const float4*)(mp);   mvb = *(const float4*)(mp + 4);
        sva = *(const float4*)(pp);   svb = *(const float4*)(pp + 4);
        eva = *(const float4*)(ep);   evb = *(const float4*)(ep + 4);
    }

    for (int k0 = 0; k0 < 800; k0 += 32){
        __syncthreads();
        *(uint4*)&As[sb*ICS + sh*16]     = ar0;
        *(uint4*)&As[sb*ICS + sh*16 + 8] = ar1;
        {
            ushort tmp[8];
            if (bvalid){
                tmp[0] = bfr(fmaf(sva.x, eva.x, mva.x));
                tmp[1] = bfr(fmaf(sva.y, eva.y, mva.y));
                tmp[2] = bfr(fmaf(sva.z, eva.z, mva.z));
                tmp[3] = bfr(fmaf(sva.w, eva.w, mva.w));
                tmp[4] = bfr(fmaf(svb.x, evb.x, mvb.x));
                tmp[5] = bfr(fmaf(svb.y, evb.y, mvb.y));
                tmp[6] = bfr(fmaf(svb.z, evb.z, mvb.z));
                tmp[7] = bfr(fmaf(svb.w, evb.w, mvb.w));
            } else {
                #pragma unroll
                for (int j2 = 0; j2 < 8; ++j2) tmp[j2] = 0;
            }
            *(uint4*)&Bsh[so*ICS + sk] = *(const uint4*)tmp;
        }
        __syncthreads();
        int kn = k0 + 32;
        if (kn < 800){   // prefetch next tile; overlaps MFMA phase
            ar0 = ((const uint4*)(ap + kn))[0]; ar1 = ((const uint4*)(ap + kn))[1];
            if (bvalid){
                mva = *(const float4*)(mp + kn);  mvb = *(const float4*)(mp + kn + 4);
                sva = *(const float4*)(pp + kn);  svb = *(const float4*)(pp + kn + 4);
                eva = *(const float4*)(ep + kn);  evb = *(const float4*)(ep + kn + 4);
            }
        }
        #pragma unroll
        for (int ks = 0; ks < 2; ++ks){
            bhalf8 a0 = *(const bhalf8*)&As[(wm*64      + l31)*ICS + ks*16 + q*8];
            bhalf8 a1 = *(const bhalf8*)&As[(wm*64 + 32 + l31)*ICS + ks*16 + q*8];
            bhalf8 bb = *(const bhalf8*)&Bsh[(wn*32 + l31)*ICS + ks*16 + q*8];
            acc0 = __builtin_amdgcn_mfma_f32_32x32x16_bf16(a0, bb, acc0, 0, 0, 0);
            acc1 = __builtin_amdgcn_mfma_f32_32x32x16_bf16(a1, bb, acc1, 0, 0, 0);
        }
    }
    int o = o0 + wn*32 + l31;
    if (o < 500){
        float bias = ball[s*580 + 70 + o];
        #pragma unroll
        for (int mt = 0; mt < 2; ++mt){
            fx16 a = mt ? acc1 : acc0;
            #pragma unroll
            for (int reg = 0; reg < 16; ++reg){
                int row = (reg & 3) + 8*(reg >> 2) + 4*q;
                int b = wm*64 + mt*32 + row;
                h3[(size_t)(s*Bn + b)*500 + o] = fmaxf(a[reg] + bias, 0.f);
            }
        }
    }
}

// ---------------- K4a: aff2 + log_softmax per (s,b) ----------------
__global__ __launch_bounds__(256) void k4a(const float* __restrict__ h3,
        const float* __restrict__ w4, const float* __restrict__ ball,
        float* __restrict__ lsw){
    int wv = threadIdx.x >> 6, lane = threadIdx.x & 63;
    int p = blockIdx.x*4 + wv;
    int s = p / Bn;
    const float* hp = &h3[(size_t)p*500];
    const float* wp = &w4[(size_t)s*5000];
    float part[10];
    #pragma unroll
    for (int o = 0; o < 10; ++o) part[o] = 0.f;
    for (int i = lane; i < 500; i += 64){
        float hv = hp[i];
        #pragma unroll
        for (int o = 0; o < 10; ++o)
            part[o] = fmaf(hv, wp[o*500 + i], part[o]);
    }
    #pragma unroll
    for (int o = 0; o < 10; ++o){
        #pragma unroll
        for (int d = 1; d < 64; d <<= 1)
            part[o] += __shfl_xor(part[o], d);
    }
    float v[10]; float m = -INFINITY;
    #pragma unroll
    for (int o = 0; o < 10; ++o){
        v[o] = part[o] + ball[s*580 + 570 + o];
        m = fmaxf(m, v[o]);
    }
    float sum = 0.f;
    #pragma unroll
    for (int o = 0; o < 10; ++o) sum += __expf(v[o] - m);
    float lse = m + __logf(sum);
    if (lane == 0){
        #pragma unroll
        for (int o = 0; o < 10; ++o) lsw[p*10 + o] = v[o] - lse;
    }
}

// ---------------- K4b: mean over samples ----------------
__global__ void k4b(const float* __restrict__ lsw, float* __restrict__ outp){
    int j = blockIdx.x * blockDim.x + threadIdx.x;
    if (j >= Bn*10) return;
    int b = j / 10, o = j % 10;
    float acc = 0.f;
    for (int s2 = 0; s2 < Sn; ++s2) acc += lsw[(s2*Bn + b)*10 + o];
    outp[j] = acc * (1.f / (float)Sn);
}

extern "C" void kernel_launch(void* const* d_in, const int* in_sizes, int n_in,
                              void* d_out, int out_size, void* d_ws, size_t ws_size,
                              hipStream_t stream){
    const float* x     = (const float*)d_in[0];
    const float* e     = (const float*)d_in[1];
    const float* mu_w  = (const float*)d_in[2];
    const float* rho_w = (const float*)d_in[3];
    const float* mu_b  = (const float*)d_in[4];
    const float* rho_b = (const float*)d_in[5];
    float* ws   = (float*)d_ws;
    float* w1     = ws;                       //     50,000 f
    float* w4     = w1 + 50000;               //    500,000 f
    float* ball   = w4 + 500000;              //     58,000 f
    float* h3     = ball + 58000;             //  6,400,000 f
    float* lsw    = h3 + 6400000;             //    128,000 f
    float* sp_all = lsw + 128000;             //    431,080 f
    ushort* h1p = (ushort*)(sp_all + 431080); // 36,864,000 u16
    ushort* h2p = h1p + 36864000;             // 10,240,000 u16
    ushort* w2r = h2p + 10240000;             //  5,120,000 u16
    float* outp = (float*)d_out;

    hipMemsetAsync(w2r, 0, (size_t)Sn*51200*2, stream);
    k00_sp  <<<(EWc + 255)/256, 256, 0, stream>>>(rho_w, rho_b, sp_all);
    k0_gen  <<<(Sn*31080 + 255)/256, 256, 0, stream>>>(e, mu_w, sp_all, mu_b, w1, w2r, w4, ball);
    k1_conv1<<<Sn*Bn, 256, 0, stream>>>(x, w1, ball, h1p);
    k2_mfma <<<Sn*32, 256, 0, stream>>>(h1p, w2r, ball, h2p);
    k3_mfma <<<Sn*8, 256, 0, stream>>>(h2p, e, mu_w, sp_all, ball, h3);
    k4a     <<<3200, 256, 0, stream>>>(h3, w4, ball, lsw);
    k4b     <<<(Bn*10 + 255)/256, 256, 0, stream>>>(lsw, outp);
}